// Round 5
// baseline (334.533 us; speedup 1.0000x reference)
//
#include <hip/hip_runtime.h>
#include <math.h>
#include <stdint.h>

#define SEQ   4096
#define HID   2048
#define HD    128
#define NROWS 16384          // BATCH*SEQ, BATCH=4

typedef __attribute__((ext_vector_type(8))) short bf16x8;   // 8 bf16 = 4 VGPRs
typedef __attribute__((ext_vector_type(4))) float f32x4;

static constexpr float OSCALE = 0.088388347648318447f;  // 1/sqrt(128), post-softmax

// ---- async global->LDS, 16B per lane; LDS dest = wave-uniform base + lane*16.
// Global source address is per-lane -> XOR-swizzle chunk placement to kill
// bank conflicts on the frag-read side (R3: unswizzled cost 44% of runtime).
using gvptr = const __attribute__((address_space(1))) void*;
using lvptr = __attribute__((address_space(3))) void*;
__device__ __forceinline__ void gld_lds16(const void* g, void* l) {
    __builtin_amdgcn_global_load_lds((gvptr)g, (lvptr)l, 16, 0, 0);
}

// ---- bf16 helpers (manual: storage is ushort)
__device__ __forceinline__ unsigned short f2bf_rne(float f) {
    union { float f; unsigned u; } v; v.f = f;
    unsigned u = v.u + 0x7fffu + ((v.u >> 16) & 1u);
    return (unsigned short)(u >> 16);
}
__device__ __forceinline__ unsigned short f2bf_tr(float f) {
    union { float f; unsigned u; } v; v.f = f;
    return (unsigned short)(v.u >> 16);
}
__device__ __forceinline__ float bf2f(unsigned short h) {
    union { unsigned u; float f; } v; v.u = ((unsigned)h) << 16;
    return v.f;
}

// ---------------------------------------------------------------------------
// prep_w: W[k][n] fp32 -> transposed bf16 hi/lo Wt[n][k] per matrix.
// ---------------------------------------------------------------------------
__global__ __launch_bounds__(256) void prep_w(
    const float* __restrict__ Wq, const float* __restrict__ Wk, const float* __restrict__ Wv,
    unsigned short* __restrict__ wth, unsigned short* __restrict__ wtl)
{
    __shared__ float T[64][68];
    const int tid = threadIdx.x;
    const int k0 = blockIdx.x * 64, n0 = blockIdx.y * 64, mm = blockIdx.z;
    const float* W = (mm == 0) ? Wq : (mm == 1) ? Wk : Wv;
    #pragma unroll
    for (int i = 0; i < 4; ++i) {
        const int fi = i * 256 + tid, kk = fi >> 4, nc = (fi & 15) * 4;
        const float4 w = *(const float4*)(W + (size_t)(k0 + kk) * HD + n0 + nc);
        T[kk][nc] = w.x; T[kk][nc + 1] = w.y; T[kk][nc + 2] = w.z; T[kk][nc + 3] = w.w;
    }
    __syncthreads();
    unsigned short* oh = wth + (size_t)mm * HD * HID;
    unsigned short* ol = wtl + (size_t)mm * HD * HID;
    #pragma unroll
    for (int i = 0; i < 4; ++i) {
        const int fi = i * 256 + tid, nn = fi >> 4, kc = (fi & 15) * 4;
        const float a = T[kc][nn], b = T[kc + 1][nn], c = T[kc + 2][nn], d = T[kc + 3][nn];
        ushort4 hv, lv;
        hv.x = f2bf_rne(a); hv.y = f2bf_rne(b); hv.z = f2bf_rne(c); hv.w = f2bf_rne(d);
        lv.x = f2bf_rne(a - bf2f(hv.x)); lv.y = f2bf_rne(b - bf2f(hv.y));
        lv.z = f2bf_rne(c - bf2f(hv.z)); lv.w = f2bf_rne(d - bf2f(hv.w));
        *(ushort4*)(oh + (size_t)(n0 + nn) * HID + k0 + kc) = hv;
        *(ushort4*)(ol + (size_t)(n0 + nn) * HID + k0 + kc) = lv;
    }
}

// ---------------------------------------------------------------------------
// qkv_fused: Q,K,V projections in ONE kernel (R4 post-mortem: per-mat kernels
// converted x to bf16 hi/lo 3x redundantly; grid 384 wasted 25% on 256 CUs).
// Grid 512 = 256 row-tiles x 2 col-halves (uniform, ~4 blocks/CU by LDS 30KB).
// Block: 64 rows x (3 mats x 64 cols). Waves 2x2: 32 rows x (3 x 32 cols).
// Q/K 3-pass hi/lo, V 1-pass. B tiles staged gld_lds w/ chunk^=row&3 swizzle.
// ---------------------------------------------------------------------------
__global__ __launch_bounds__(256, 3) void qkv_fused(
    const float* __restrict__ x,
    const float* __restrict__ bq, const float* __restrict__ bk, const float* __restrict__ bv,
    const unsigned short* __restrict__ wth, const unsigned short* __restrict__ wtl,
    unsigned short* __restrict__ qh, unsigned short* __restrict__ ql,
    unsigned short* __restrict__ kh, unsigned short* __restrict__ kl,
    unsigned short* __restrict__ vth)
{
    __shared__ unsigned short Ah[64][40], Al[64][40];   // x hi/lo (ds-written, padded)
    __shared__ unsigned short Bt[5][64][32];            // 0=Qh 1=Ql 2=Kh 3=Kl 4=Vh

    const int tid = threadIdx.x, wave = tid >> 6, lane = tid & 63;
    const int l15 = lane & 15, q4 = lane >> 4;
    const int wr = wave >> 1, wc = wave & 1;
    const int r0 = (blockIdx.x >> 1) * 64;
    const int hc = blockIdx.x & 1;                      // col half (0..63 / 64..127)

    const unsigned short* wsrc0 = wth + (size_t)hc * 64 * HID;                 // Qh
    const unsigned short* wsrc1 = wtl + (size_t)hc * 64 * HID;                 // Ql
    const unsigned short* wsrc2 = wth + (size_t)HD * HID + (size_t)hc * 64 * HID;   // Kh
    const unsigned short* wsrc3 = wtl + (size_t)HD * HID + (size_t)hc * 64 * HID;   // Kl
    const unsigned short* wsrc4 = wth + (size_t)2 * HD * HID + (size_t)hc * 64 * HID; // Vh

    // B staging: wave stages rows [wave*16, +16) of each array; 1KB/instr.
    const int srow = wave * 16 + (lane >> 2);
    const int schunk = ((lane & 3) ^ ((lane >> 2) & 3)) * 8;   // swizzled src offset (shorts)
    // B frag read: row r in tile -> physical chunk = q4 ^ (r&3); r&3 == l15&3
    const int pchunk = (q4 ^ (l15 & 3)) * 8;
    const int bro = wc * 32;

    f32x4 accq[2][2], acck[2][2], accv[2][2];
    #pragma unroll
    for (int i = 0; i < 2; ++i)
        #pragma unroll
        for (int j = 0; j < 2; ++j) {
            accq[i][j] = (f32x4){0.f, 0.f, 0.f, 0.f};
            acck[i][j] = (f32x4){0.f, 0.f, 0.f, 0.f};
            accv[i][j] = (f32x4){0.f, 0.f, 0.f, 0.f};
        }

    for (int k0 = 0; k0 < HID; k0 += 32) {
        float4 xv[2];
        #pragma unroll
        for (int i = 0; i < 2; ++i) {
            const int fi = i * 256 + tid, row = fi >> 3, kc = (fi & 7) * 4;
            xv[i] = *(const float4*)(x + (size_t)(r0 + row) * HID + k0 + kc);
        }
        __syncthreads();   // prior iteration's frag reads done
        {   // stage 5 W tiles, swizzled
            gld_lds16(wsrc0 + (size_t)srow * HID + k0 + schunk, &Bt[0][wave * 16][0]);
            gld_lds16(wsrc1 + (size_t)srow * HID + k0 + schunk, &Bt[1][wave * 16][0]);
            gld_lds16(wsrc2 + (size_t)srow * HID + k0 + schunk, &Bt[2][wave * 16][0]);
            gld_lds16(wsrc3 + (size_t)srow * HID + k0 + schunk, &Bt[3][wave * 16][0]);
            gld_lds16(wsrc4 + (size_t)srow * HID + k0 + schunk, &Bt[4][wave * 16][0]);
        }
        #pragma unroll
        for (int i = 0; i < 2; ++i) {   // x fp32 -> bf16 hi/lo -> LDS (ONCE per block)
            const int fi = i * 256 + tid, row = fi >> 3, kc = (fi & 7) * 4;
            ushort4 hv, lv;
            hv.x = f2bf_tr(xv[i].x); hv.y = f2bf_tr(xv[i].y);
            hv.z = f2bf_tr(xv[i].z); hv.w = f2bf_tr(xv[i].w);
            lv.x = f2bf_tr(xv[i].x - bf2f(hv.x)); lv.y = f2bf_tr(xv[i].y - bf2f(hv.y));
            lv.z = f2bf_tr(xv[i].z - bf2f(hv.z)); lv.w = f2bf_tr(xv[i].w - bf2f(hv.w));
            *(ushort4*)&Ah[row][kc] = hv;
            *(ushort4*)&Al[row][kc] = lv;
        }
        __syncthreads();

        bf16x8 ah[2], al[2];
        #pragma unroll
        for (int mt = 0; mt < 2; ++mt) {
            ah[mt] = *(const bf16x8*)&Ah[wr * 32 + mt * 16 + l15][q4 * 8];
            al[mt] = *(const bf16x8*)&Al[wr * 32 + mt * 16 + l15][q4 * 8];
        }
        #pragma unroll
        for (int nt = 0; nt < 2; ++nt) {
            const int br = bro + nt * 16 + l15;
            const bf16x8 qbh = *(const bf16x8*)&Bt[0][br][pchunk];
            const bf16x8 qbl = *(const bf16x8*)&Bt[1][br][pchunk];
            #pragma unroll
            for (int mt = 0; mt < 2; ++mt) {
                accq[mt][nt] = __builtin_amdgcn_mfma_f32_16x16x32_bf16(ah[mt], qbh, accq[mt][nt], 0, 0, 0);
                accq[mt][nt] = __builtin_amdgcn_mfma_f32_16x16x32_bf16(ah[mt], qbl, accq[mt][nt], 0, 0, 0);
                accq[mt][nt] = __builtin_amdgcn_mfma_f32_16x16x32_bf16(al[mt], qbh, accq[mt][nt], 0, 0, 0);
            }
            const bf16x8 kbh = *(const bf16x8*)&Bt[2][br][pchunk];
            const bf16x8 kbl = *(const bf16x8*)&Bt[3][br][pchunk];
            #pragma unroll
            for (int mt = 0; mt < 2; ++mt) {
                acck[mt][nt] = __builtin_amdgcn_mfma_f32_16x16x32_bf16(ah[mt], kbh, acck[mt][nt], 0, 0, 0);
                acck[mt][nt] = __builtin_amdgcn_mfma_f32_16x16x32_bf16(ah[mt], kbl, acck[mt][nt], 0, 0, 0);
                acck[mt][nt] = __builtin_amdgcn_mfma_f32_16x16x32_bf16(al[mt], kbh, acck[mt][nt], 0, 0, 0);
            }
            const bf16x8 vbh = *(const bf16x8*)&Bt[4][br][pchunk];
            #pragma unroll
            for (int mt = 0; mt < 2; ++mt)
                accv[mt][nt] = __builtin_amdgcn_mfma_f32_16x16x32_bf16(ah[mt], vbh, accv[mt][nt], 0, 0, 0);
        }
    }

    // epilogue. C-frag: col=l15(+tile), rows=q4*4+reg.
    #pragma unroll
    for (int nt = 0; nt < 2; ++nt) {
        const int col = hc * 64 + wc * 32 + nt * 16 + l15;
        const float bbq = bq[col], bbk = bk[col], bbv = bv[col];
        #pragma unroll
        for (int mt = 0; mt < 2; ++mt) {
            const int Rb = r0 + wr * 32 + mt * 16 + q4 * 4;
            #pragma unroll
            for (int r = 0; r < 4; ++r) {
                const float vq = accq[mt][nt][r] + bbq;
                const unsigned short hq = f2bf_rne(vq);
                qh[(size_t)(Rb + r) * HD + col] = hq;
                ql[(size_t)(Rb + r) * HD + col] = f2bf_rne(vq - bf2f(hq));
                const float vk = acck[mt][nt][r] + bbk;
                const unsigned short hk = f2bf_rne(vk);
                kh[(size_t)(Rb + r) * HD + col] = hk;
                kl[(size_t)(Rb + r) * HD + col] = f2bf_rne(vk - bf2f(hk));
            }
            const int bi = Rb >> 12, s0 = Rb & 4095;   // V transposed: regs = consecutive s
            ushort4 pv;
            pv.x = f2bf_rne(accv[mt][nt][0] + bbv);
            pv.y = f2bf_rne(accv[mt][nt][1] + bbv);
            pv.z = f2bf_rne(accv[mt][nt][2] + bbv);
            pv.w = f2bf_rne(accv[mt][nt][3] + bbv);
            *(ushort4*)(vth + ((size_t)(bi * HD + col)) * SEQ + s0) = pv;
        }
    }
}

// ---------------------------------------------------------------------------
// flash_mfma: causal flash on MFMA (unchanged from R4). BQ=64, BK=64.
// Grid: 4b x 32 pairs(t,63-t) x 4 kv-quarters = 512 blocks.
// ---------------------------------------------------------------------------
__global__ __launch_bounds__(256, 2) void flash_mfma(
    const unsigned short* __restrict__ qh, const unsigned short* __restrict__ ql,
    const unsigned short* __restrict__ kh, const unsigned short* __restrict__ kl,
    const unsigned short* __restrict__ vth,
    unsigned short* __restrict__ oPb, float* __restrict__ mP, float* __restrict__ lP)
{
    __shared__ unsigned short Kh[64][128], Kl[64][128];   // [kvrow][d], swizzled
    __shared__ unsigned short Vt[128][64];                // [d][kvrow], swizzled
    __shared__ unsigned short Ps[4][16][72];              // per-wave P, padded

    const int tid = threadIdx.x, wave = tid >> 6, lane = tid & 63;
    const int l15 = lane & 15, q4 = lane >> 4;
    const int h = blockIdx.x & 3, pair = (blockIdx.x >> 2) & 31, b = blockIdx.x >> 7;

    const int krow_l = lane >> 4;                               // 0..3
    const int vrow_l = lane >> 3;                               // 0..7
    const int vsc = ((lane & 7) ^ (vrow_l & 7)) * 8;            // Vt src chunk
    const int kkey7 = l15 & 7;
    const int vkey7 = l15 & 7;

    for (int side = 0; side < 2; ++side) {
        const int tt = side ? (63 - pair) : pair;
        const int n = tt + 1;
        const int j0 = (n * h) >> 2, j1 = (n * (h + 1)) >> 2;

        const int qrow = b * SEQ + tt * 64 + wave * 16 + l15;
        bf16x8 aqh[4], aql[4];
        #pragma unroll
        for (int ks = 0; ks < 4; ++ks) {
            aqh[ks] = *(const bf16x8*)(qh + (size_t)qrow * HD + ks * 32 + q4 * 8);
            aql[ks] = *(const bf16x8*)(ql + (size_t)qrow * HD + ks * 32 + q4 * 8);
        }
        f32x4 oa[8];
        #pragma unroll
        for (int d = 0; d < 8; ++d) oa[d] = (f32x4){0.f, 0.f, 0.f, 0.f};
        float m_r[4] = {-INFINITY, -INFINITY, -INFINITY, -INFINITY};
        float l_r[4] = {0.f, 0.f, 0.f, 0.f};

        for (int j = j0; j < j1; ++j) {
            __syncthreads();
            {   // stage K hi/lo + Vt, chunk-swizzled
                const size_t kb = (size_t)b * SEQ + j * 64;
                #pragma unroll
                for (int c = 0; c < 4; ++c) {
                    const int rl = c * 4 + krow_l;
                    const int sc = (l15 ^ (rl & 7)) * 8;
                    const size_t gr = (kb + wave * 16 + rl) * HD + sc;
                    gld_lds16(kh + gr, &Kh[wave * 16 + c * 4][0]);
                    gld_lds16(kl + gr, &Kl[wave * 16 + c * 4][0]);
                }
                #pragma unroll
                for (int c = 0; c < 4; ++c)
                    gld_lds16(vth + ((size_t)(b * HD + wave * 32 + c * 8 + vrow_l)) * SEQ
                                  + j * 64 + vsc,
                              &Vt[wave * 32 + c * 8][0]);
            }
            __syncthreads();

            f32x4 s[4];
            #pragma unroll
            for (int nt = 0; nt < 4; ++nt) s[nt] = (f32x4){0.f, 0.f, 0.f, 0.f};
            #pragma unroll
            for (int ks = 0; ks < 4; ++ks) {
                const int pc = ((ks * 4 + q4) ^ kkey7) * 8;
                #pragma unroll
                for (int nt = 0; nt < 4; ++nt) {
                    const bf16x8 bh = *(const bf16x8*)&Kh[nt * 16 + l15][pc];
                    const bf16x8 bl = *(const bf16x8*)&Kl[nt * 16 + l15][pc];
                    s[nt] = __builtin_amdgcn_mfma_f32_16x16x32_bf16(aqh[ks], bh, s[nt], 0, 0, 0);
                    s[nt] = __builtin_amdgcn_mfma_f32_16x16x32_bf16(aql[ks], bh, s[nt], 0, 0, 0);
                    s[nt] = __builtin_amdgcn_mfma_f32_16x16x32_bf16(aqh[ks], bl, s[nt], 0, 0, 0);
                }
            }
            if (j == tt) {
                #pragma unroll
                for (int nt = 0; nt < 4; ++nt) {
                    const int cl = nt * 16 + l15;
                    #pragma unroll
                    for (int r = 0; r < 4; ++r) {
                        const int rl = wave * 16 + q4 * 4 + r;
                        if (cl > rl) s[nt][r] = -INFINITY;
                    }
                }
            }
            #pragma unroll
            for (int r = 0; r < 4; ++r) {
                float mt = fmaxf(fmaxf(s[0][r], s[1][r]), fmaxf(s[2][r], s[3][r]));
                mt = fmaxf(mt, __shfl_xor(mt, 1));
                mt = fmaxf(mt, __shfl_xor(mt, 2));
                mt = fmaxf(mt, __shfl_xor(mt, 4));
                mt = fmaxf(mt, __shfl_xor(mt, 8));
                const float mn = fmaxf(m_r[r], mt);
                const float al = __expf(m_r[r] - mn);
                m_r[r] = mn;
                const float p0 = __expf(s[0][r] - mn), p1 = __expf(s[1][r] - mn);
                const float p2 = __expf(s[2][r] - mn), p3 = __expf(s[3][r] - mn);
                Ps[wave][q4 * 4 + r][l15]      = f2bf_tr(p0);
                Ps[wave][q4 * 4 + r][16 + l15] = f2bf_tr(p1);
                Ps[wave][q4 * 4 + r][32 + l15] = f2bf_tr(p2);
                Ps[wave][q4 * 4 + r][48 + l15] = f2bf_tr(p3);
                float ps = p0 + p1 + p2 + p3;
                ps += __shfl_xor(ps, 1); ps += __shfl_xor(ps, 2);
                ps += __shfl_xor(ps, 4); ps += __shfl_xor(ps, 8);
                l_r[r] = l_r[r] * al + ps;
                #pragma unroll
                for (int d = 0; d < 8; ++d) oa[d][r] *= al;
            }
            const bf16x8 ap0 = *(const bf16x8*)&Ps[wave][l15][q4 * 8];
            const bf16x8 ap1 = *(const bf16x8*)&Ps[wave][l15][32 + q4 * 8];
            #pragma unroll
            for (int d = 0; d < 8; ++d) {
                const bf16x8 bv0 = *(const bf16x8*)&Vt[d * 16 + l15][(q4 ^ vkey7) * 8];
                const bf16x8 bv1 = *(const bf16x8*)&Vt[d * 16 + l15][((4 + q4) ^ vkey7) * 8];
                oa[d] = __builtin_amdgcn_mfma_f32_16x16x32_bf16(ap0, bv0, oa[d], 0, 0, 0);
                oa[d] = __builtin_amdgcn_mfma_f32_16x16x32_bf16(ap1, bv1, oa[d], 0, 0, 0);
            }
        }

        const int R0 = b * SEQ + tt * 64 + wave * 16 + q4 * 4;
        unsigned short* op = oPb + (size_t)h * NROWS * HD;
        #pragma unroll
        for (int d = 0; d < 8; ++d)
            #pragma unroll
            for (int r = 0; r < 4; ++r)
                op[(size_t)(R0 + r) * HD + d * 16 + l15] = f2bf_rne(oa[d][r]);
        if (l15 == 0) {
            #pragma unroll
            for (int r = 0; r < 4; ++r) {
                mP[h * NROWS + R0 + r] = m_r[r];
                lP[h * NROWS + R0 + r] = l_r[r];
            }
        }
    }
}

// ---------------------------------------------------------------------------
// merge the four kv-quarter partials; apply 1/l and OSCALE.
// ---------------------------------------------------------------------------
__global__ __launch_bounds__(256) void flash_merge(
    const unsigned short* __restrict__ oPb, const float* __restrict__ mP,
    const float* __restrict__ lP, float* __restrict__ out)
{
    const int idx = blockIdx.x * 256 + threadIdx.x;   // per float4
    const int r = idx >> 5, c = (idx & 31) * 4;
    float m[4], l[4];
    #pragma unroll
    for (int i = 0; i < 4; ++i) { m[i] = mP[i * NROWS + r]; l[i] = lP[i * NROWS + r]; }
    float M = fmaxf(fmaxf(m[0], m[1]), fmaxf(m[2], m[3]));
    float a[4], lsum = 0.f;
    #pragma unroll
    for (int i = 0; i < 4; ++i) { a[i] = __expf(m[i] - M); lsum += l[i] * a[i]; }
    const float inv = OSCALE / lsum;
    float ox = 0.f, oy = 0.f, oz = 0.f, ow = 0.f;
    #pragma unroll
    for (int i = 0; i < 4; ++i) {
        const ushort4 ov = *(const ushort4*)(oPb + (size_t)i * NROWS * HD + (size_t)r * HD + c);
        ox += a[i] * bf2f(ov.x); oy += a[i] * bf2f(ov.y);
        oz += a[i] * bf2f(ov.z); ow += a[i] * bf2f(ov.w);
    }
    float4 o; o.x = ox * inv; o.y = oy * inv; o.z = oz * inv; o.w = ow * inv;
    *(float4*)(out + (size_t)r * HD + c) = o;
}

// ---------------------------------------------------------------------------
extern "C" void kernel_launch(void* const* d_in, const int* in_sizes, int n_in,
                              void* d_out, int out_size, void* d_ws, size_t ws_size,
                              hipStream_t stream)
{
    (void)in_sizes; (void)n_in; (void)out_size; (void)ws_size;
    const float* x  = (const float*)d_in[0];
    const float* Wq = (const float*)d_in[1];
    const float* bq = (const float*)d_in[2];
    const float* Wk = (const float*)d_in[3];
    const float* bk = (const float*)d_in[4];
    const float* Wv = (const float*)d_in[5];
    const float* bv = (const float*)d_in[6];
    float* out = (float*)d_out;

    // workspace layout (bytes): ~41.4 MB total
    char* w = (char*)d_ws;
    unsigned short* qh  = (unsigned short*)(w);
    unsigned short* ql  = (unsigned short*)(w + 4194304);
    unsigned short* kh  = (unsigned short*)(w + 8388608);
    unsigned short* kl  = (unsigned short*)(w + 12582912);
    unsigned short* vth = (unsigned short*)(w + 16777216);
    unsigned short* wth = (unsigned short*)(w + 20971520);
    unsigned short* wtl = (unsigned short*)(w + 22544384);
    unsigned short* oPb = (unsigned short*)(w + 24117248);   // 4 x NROWS x HD bf16
    float* mP = (float*)(w + 40894464);                      // 4 x NROWS
    float* lP = (float*)(w + 41156608);                      // 4 x NROWS

    prep_w<<<dim3(32, 2, 3), 256, 0, stream>>>(Wq, Wk, Wv, wth, wtl);
    qkv_fused<<<512, 256, 0, stream>>>(x, bq, bk, bv, wth, wtl, qh, ql, kh, kl, vth);
    flash_mfma<<<512, 256, 0, stream>>>(qh, ql, kh, kl, vth, oPb, mP, lP);
    flash_merge<<<2048, 256, 0, stream>>>(oPb, mP, lP, out);
}

// Round 6
// 320.122 us; speedup vs baseline: 1.0450x; 1.0450x over previous
//
#include <hip/hip_runtime.h>
#include <math.h>
#include <stdint.h>

#define SEQ   4096
#define HID   2048
#define HD    128
#define NROWS 16384          // BATCH*SEQ, BATCH=4

typedef __attribute__((ext_vector_type(8))) short bf16x8;   // 8 bf16 = 4 VGPRs
typedef __attribute__((ext_vector_type(4))) float f32x4;

static constexpr float OSCALE = 0.088388347648318447f;  // 1/sqrt(128), post-softmax

// ---- async global->LDS, 16B per lane; LDS dest = wave-uniform base + lane*16.
// Global source address is per-lane -> XOR-swizzle chunk placement to kill
// bank conflicts on the frag-read side (R3: unswizzled cost 44% of runtime).
using gvptr = const __attribute__((address_space(1))) void*;
using lvptr = __attribute__((address_space(3))) void*;
__device__ __forceinline__ void gld_lds16(const void* g, void* l) {
    __builtin_amdgcn_global_load_lds((gvptr)g, (lvptr)l, 16, 0, 0);
}

// ---- bf16 helpers (manual: storage is ushort)
__device__ __forceinline__ unsigned short f2bf_rne(float f) {
    union { float f; unsigned u; } v; v.f = f;
    unsigned u = v.u + 0x7fffu + ((v.u >> 16) & 1u);
    return (unsigned short)(u >> 16);
}
__device__ __forceinline__ unsigned short f2bf_tr(float f) {
    union { float f; unsigned u; } v; v.f = f;
    return (unsigned short)(v.u >> 16);
}
__device__ __forceinline__ float bf2f(unsigned short h) {
    union { unsigned u; float f; } v; v.u = ((unsigned)h) << 16;
    return v.f;
}

// ---------------------------------------------------------------------------
// prep_w: W[k][n] fp32 -> transposed bf16 hi/lo Wt[n][k] per matrix.
// ---------------------------------------------------------------------------
__global__ __launch_bounds__(256) void prep_w(
    const float* __restrict__ Wq, const float* __restrict__ Wk, const float* __restrict__ Wv,
    unsigned short* __restrict__ wth, unsigned short* __restrict__ wtl)
{
    __shared__ float T[64][68];
    const int tid = threadIdx.x;
    const int k0 = blockIdx.x * 64, n0 = blockIdx.y * 64, mm = blockIdx.z;
    const float* W = (mm == 0) ? Wq : (mm == 1) ? Wk : Wv;
    #pragma unroll
    for (int i = 0; i < 4; ++i) {
        const int fi = i * 256 + tid, kk = fi >> 4, nc = (fi & 15) * 4;
        const float4 w = *(const float4*)(W + (size_t)(k0 + kk) * HD + n0 + nc);
        T[kk][nc] = w.x; T[kk][nc + 1] = w.y; T[kk][nc + 2] = w.z; T[kk][nc + 3] = w.w;
    }
    __syncthreads();
    unsigned short* oh = wth + (size_t)mm * HD * HID;
    unsigned short* ol = wtl + (size_t)mm * HD * HID;
    #pragma unroll
    for (int i = 0; i < 4; ++i) {
        const int fi = i * 256 + tid, nn = fi >> 4, kc = (fi & 15) * 4;
        const float a = T[kc][nn], b = T[kc + 1][nn], c = T[kc + 2][nn], d = T[kc + 3][nn];
        ushort4 hv, lv;
        hv.x = f2bf_rne(a); hv.y = f2bf_rne(b); hv.z = f2bf_rne(c); hv.w = f2bf_rne(d);
        lv.x = f2bf_rne(a - bf2f(hv.x)); lv.y = f2bf_rne(b - bf2f(hv.y));
        lv.z = f2bf_rne(c - bf2f(hv.z)); lv.w = f2bf_rne(d - bf2f(hv.w));
        *(ushort4*)(oh + (size_t)(n0 + nn) * HID + k0 + kc) = hv;
        *(ushort4*)(ol + (size_t)(n0 + nn) * HID + k0 + kc) = lv;
    }
}

// ---------------------------------------------------------------------------
// qkv_fused (R6): BK=64 + x register-prefetch. R5 post-mortem: the k-loop
// loaded x(k) at iter top and used it one barrier later -> ~900cy HBM latency
// exposed per thin iteration (64 iters) = latency-bound at MfmaUtil 20%.
// Now: 32 fat iters; x(k+1) loads issue right after sync2, consumed next
// iter -> load-to-use spans the whole MFMA section (~2000+cy > 900cy).
// Grid 512 = 256 row-tiles x 2 col-halves. LDS 59.4KB -> 2 blocks/CU.
// ---------------------------------------------------------------------------
__global__ __launch_bounds__(256, 2) void qkv_fused(
    const float* __restrict__ x,
    const float* __restrict__ bq, const float* __restrict__ bk, const float* __restrict__ bv,
    const unsigned short* __restrict__ wth, const unsigned short* __restrict__ wtl,
    unsigned short* __restrict__ qh, unsigned short* __restrict__ ql,
    unsigned short* __restrict__ kh, unsigned short* __restrict__ kl,
    unsigned short* __restrict__ vth)
{
    __shared__ unsigned short Ah[64][72], Al[64][72];   // x hi/lo (ds-written, padded)
    __shared__ unsigned short Bt[5][64][64];            // 0=Qh 1=Ql 2=Kh 3=Kl 4=Vh (swizzled)

    const int tid = threadIdx.x, wave = tid >> 6, lane = tid & 63;
    const int l15 = lane & 15, q4 = lane >> 4;
    const int wr = wave >> 1, wc = wave & 1;
    const int r0 = (blockIdx.x >> 1) * 64;
    const int hc = blockIdx.x & 1;                      // col half (0..63 / 64..127)

    const unsigned short* wsrc[5] = {
        wth + (size_t)hc * 64 * HID,                                   // Qh
        wtl + (size_t)hc * 64 * HID,                                   // Ql
        wth + (size_t)HD * HID + (size_t)hc * 64 * HID,                // Kh
        wtl + (size_t)HD * HID + (size_t)hc * 64 * HID,                // Kl
        wth + (size_t)2 * HD * HID + (size_t)hc * 64 * HID };          // Vh

    // weight staging: wave stages rows [wave*16,+16) per array; 2 instr/array.
    // lane -> row_in_8group = lane>>3, physical chunk = lane&7,
    // source logical chunk = (lane&7) ^ (lane>>3)   (key = row&7)
    const int srow_off = lane >> 3;
    const int schunk   = ((lane & 7) ^ (lane >> 3)) * 8;   // shorts

    f32x4 accq[2][2], acck[2][2], accv[2][2];
    #pragma unroll
    for (int i = 0; i < 2; ++i)
        #pragma unroll
        for (int j = 0; j < 2; ++j) {
            accq[i][j] = (f32x4){0.f, 0.f, 0.f, 0.f};
            acck[i][j] = (f32x4){0.f, 0.f, 0.f, 0.f};
            accv[i][j] = (f32x4){0.f, 0.f, 0.f, 0.f};
        }

    const float* xbase = x + (size_t)r0 * HID;

    // preload first x slab (64 rows x 64 k): 4 float4 per thread
    float4 xv[4];
    #pragma unroll
    for (int i = 0; i < 4; ++i) {
        const int fi = i * 256 + tid, row = fi >> 4, kc = (fi & 15) * 4;
        xv[i] = *(const float4*)(xbase + (size_t)row * HID + kc);
    }

    for (int k0 = 0; k0 < HID; k0 += 64) {
        __syncthreads();   // prior iter's frag reads done
        {   // stage 5 W tiles for this k-slab (L2-hot, covered by conversion)
            #pragma unroll
            for (int a = 0; a < 5; ++a) {
                #pragma unroll
                for (int c = 0; c < 2; ++c) {
                    const int row = wave * 16 + c * 8 + srow_off;
                    gld_lds16(wsrc[a] + (size_t)row * HID + k0 + schunk,
                              &Bt[a][wave * 16 + c * 8][0]);
                }
            }
        }
        #pragma unroll
        for (int i = 0; i < 4; ++i) {   // convert current x slab -> LDS hi/lo
            const int fi = i * 256 + tid, row = fi >> 4, kc = (fi & 15) * 4;
            ushort4 hv, lv;
            hv.x = f2bf_tr(xv[i].x); hv.y = f2bf_tr(xv[i].y);
            hv.z = f2bf_tr(xv[i].z); hv.w = f2bf_tr(xv[i].w);
            lv.x = f2bf_tr(xv[i].x - bf2f(hv.x)); lv.y = f2bf_tr(xv[i].y - bf2f(hv.y));
            lv.z = f2bf_tr(xv[i].z - bf2f(hv.z)); lv.w = f2bf_tr(xv[i].w - bf2f(hv.w));
            *(ushort4*)&Ah[row][kc] = hv;
            *(ushort4*)&Al[row][kc] = lv;
        }
        __syncthreads();

        // prefetch NEXT x slab now — consumed next iteration (HBM latency
        // hidden behind the MFMA section below)
        const int kn = (k0 + 64 < HID) ? (k0 + 64) : 0;
        #pragma unroll
        for (int i = 0; i < 4; ++i) {
            const int fi = i * 256 + tid, row = fi >> 4, kc = (fi & 15) * 4;
            xv[i] = *(const float4*)(xbase + (size_t)row * HID + kn + kc);
        }

        #pragma unroll
        for (int ks = 0; ks < 2; ++ks) {
            bf16x8 ah[2], al[2];
            #pragma unroll
            for (int mt = 0; mt < 2; ++mt) {
                ah[mt] = *(const bf16x8*)&Ah[wr * 32 + mt * 16 + l15][ks * 32 + q4 * 8];
                al[mt] = *(const bf16x8*)&Al[wr * 32 + mt * 16 + l15][ks * 32 + q4 * 8];
            }
            const int pc = ((ks * 4 + q4) ^ (l15 & 7)) * 8;   // swizzled B chunk
            #pragma unroll
            for (int nt = 0; nt < 2; ++nt) {
                const int br = wc * 32 + nt * 16 + l15;
                const bf16x8 qbh = *(const bf16x8*)&Bt[0][br][pc];
                const bf16x8 qbl = *(const bf16x8*)&Bt[1][br][pc];
                #pragma unroll
                for (int mt = 0; mt < 2; ++mt) {
                    accq[mt][nt] = __builtin_amdgcn_mfma_f32_16x16x32_bf16(ah[mt], qbh, accq[mt][nt], 0, 0, 0);
                    accq[mt][nt] = __builtin_amdgcn_mfma_f32_16x16x32_bf16(ah[mt], qbl, accq[mt][nt], 0, 0, 0);
                    accq[mt][nt] = __builtin_amdgcn_mfma_f32_16x16x32_bf16(al[mt], qbh, accq[mt][nt], 0, 0, 0);
                }
                const bf16x8 kbh = *(const bf16x8*)&Bt[2][br][pc];
                const bf16x8 kbl = *(const bf16x8*)&Bt[3][br][pc];
                #pragma unroll
                for (int mt = 0; mt < 2; ++mt) {
                    acck[mt][nt] = __builtin_amdgcn_mfma_f32_16x16x32_bf16(ah[mt], kbh, acck[mt][nt], 0, 0, 0);
                    acck[mt][nt] = __builtin_amdgcn_mfma_f32_16x16x32_bf16(ah[mt], kbl, acck[mt][nt], 0, 0, 0);
                    acck[mt][nt] = __builtin_amdgcn_mfma_f32_16x16x32_bf16(al[mt], kbh, acck[mt][nt], 0, 0, 0);
                }
                const bf16x8 vbh = *(const bf16x8*)&Bt[4][br][pc];
                #pragma unroll
                for (int mt = 0; mt < 2; ++mt)
                    accv[mt][nt] = __builtin_amdgcn_mfma_f32_16x16x32_bf16(ah[mt], vbh, accv[mt][nt], 0, 0, 0);
            }
        }
    }

    // epilogue. C-frag: col=l15(+tile), rows=q4*4+reg.
    #pragma unroll
    for (int nt = 0; nt < 2; ++nt) {
        const int col = hc * 64 + wc * 32 + nt * 16 + l15;
        const float bbq = bq[col], bbk = bk[col], bbv = bv[col];
        #pragma unroll
        for (int mt = 0; mt < 2; ++mt) {
            const int Rb = r0 + wr * 32 + mt * 16 + q4 * 4;
            #pragma unroll
            for (int r = 0; r < 4; ++r) {
                const float vq = accq[mt][nt][r] + bbq;
                const unsigned short hq = f2bf_rne(vq);
                qh[(size_t)(Rb + r) * HD + col] = hq;
                ql[(size_t)(Rb + r) * HD + col] = f2bf_rne(vq - bf2f(hq));
                const float vk = acck[mt][nt][r] + bbk;
                const unsigned short hk = f2bf_rne(vk);
                kh[(size_t)(Rb + r) * HD + col] = hk;
                kl[(size_t)(Rb + r) * HD + col] = f2bf_rne(vk - bf2f(hk));
            }
            const int bi = Rb >> 12, s0 = Rb & 4095;   // V transposed: regs = consecutive s
            ushort4 pv;
            pv.x = f2bf_rne(accv[mt][nt][0] + bbv);
            pv.y = f2bf_rne(accv[mt][nt][1] + bbv);
            pv.z = f2bf_rne(accv[mt][nt][2] + bbv);
            pv.w = f2bf_rne(accv[mt][nt][3] + bbv);
            *(ushort4*)(vth + ((size_t)(bi * HD + col)) * SEQ + s0) = pv;
        }
    }
}

// ---------------------------------------------------------------------------
// flash_mfma: causal flash on MFMA (unchanged from R5). BQ=64, BK=64.
// Grid: 4b x 32 pairs(t,63-t) x 4 kv-quarters = 512 blocks.
// ---------------------------------------------------------------------------
__global__ __launch_bounds__(256, 2) void flash_mfma(
    const unsigned short* __restrict__ qh, const unsigned short* __restrict__ ql,
    const unsigned short* __restrict__ kh, const unsigned short* __restrict__ kl,
    const unsigned short* __restrict__ vth,
    unsigned short* __restrict__ oPb, float* __restrict__ mP, float* __restrict__ lP)
{
    __shared__ unsigned short Kh[64][128], Kl[64][128];   // [kvrow][d], swizzled
    __shared__ unsigned short Vt[128][64];                // [d][kvrow], swizzled
    __shared__ unsigned short Ps[4][16][72];              // per-wave P, padded

    const int tid = threadIdx.x, wave = tid >> 6, lane = tid & 63;
    const int l15 = lane & 15, q4 = lane >> 4;
    const int h = blockIdx.x & 3, pair = (blockIdx.x >> 2) & 31, b = blockIdx.x >> 7;

    const int krow_l = lane >> 4;                               // 0..3
    const int vrow_l = lane >> 3;                               // 0..7
    const int vsc = ((lane & 7) ^ (vrow_l & 7)) * 8;            // Vt src chunk
    const int kkey7 = l15 & 7;
    const int vkey7 = l15 & 7;

    for (int side = 0; side < 2; ++side) {
        const int tt = side ? (63 - pair) : pair;
        const int n = tt + 1;
        const int j0 = (n * h) >> 2, j1 = (n * (h + 1)) >> 2;

        const int qrow = b * SEQ + tt * 64 + wave * 16 + l15;
        bf16x8 aqh[4], aql[4];
        #pragma unroll
        for (int ks = 0; ks < 4; ++ks) {
            aqh[ks] = *(const bf16x8*)(qh + (size_t)qrow * HD + ks * 32 + q4 * 8);
            aql[ks] = *(const bf16x8*)(ql + (size_t)qrow * HD + ks * 32 + q4 * 8);
        }
        f32x4 oa[8];
        #pragma unroll
        for (int d = 0; d < 8; ++d) oa[d] = (f32x4){0.f, 0.f, 0.f, 0.f};
        float m_r[4] = {-INFINITY, -INFINITY, -INFINITY, -INFINITY};
        float l_r[4] = {0.f, 0.f, 0.f, 0.f};

        for (int j = j0; j < j1; ++j) {
            __syncthreads();
            {   // stage K hi/lo + Vt, chunk-swizzled
                const size_t kb = (size_t)b * SEQ + j * 64;
                #pragma unroll
                for (int c = 0; c < 4; ++c) {
                    const int rl = c * 4 + krow_l;
                    const int sc = (l15 ^ (rl & 7)) * 8;
                    const size_t gr = (kb + wave * 16 + rl) * HD + sc;
                    gld_lds16(kh + gr, &Kh[wave * 16 + c * 4][0]);
                    gld_lds16(kl + gr, &Kl[wave * 16 + c * 4][0]);
                }
                #pragma unroll
                for (int c = 0; c < 4; ++c)
                    gld_lds16(vth + ((size_t)(b * HD + wave * 32 + c * 8 + vrow_l)) * SEQ
                                  + j * 64 + vsc,
                              &Vt[wave * 32 + c * 8][0]);
            }
            __syncthreads();

            f32x4 s[4];
            #pragma unroll
            for (int nt = 0; nt < 4; ++nt) s[nt] = (f32x4){0.f, 0.f, 0.f, 0.f};
            #pragma unroll
            for (int ks = 0; ks < 4; ++ks) {
                const int pc = ((ks * 4 + q4) ^ kkey7) * 8;
                #pragma unroll
                for (int nt = 0; nt < 4; ++nt) {
                    const bf16x8 bh = *(const bf16x8*)&Kh[nt * 16 + l15][pc];
                    const bf16x8 bl = *(const bf16x8*)&Kl[nt * 16 + l15][pc];
                    s[nt] = __builtin_amdgcn_mfma_f32_16x16x32_bf16(aqh[ks], bh, s[nt], 0, 0, 0);
                    s[nt] = __builtin_amdgcn_mfma_f32_16x16x32_bf16(aql[ks], bh, s[nt], 0, 0, 0);
                    s[nt] = __builtin_amdgcn_mfma_f32_16x16x32_bf16(aqh[ks], bl, s[nt], 0, 0, 0);
                }
            }
            if (j == tt) {
                #pragma unroll
                for (int nt = 0; nt < 4; ++nt) {
                    const int cl = nt * 16 + l15;
                    #pragma unroll
                    for (int r = 0; r < 4; ++r) {
                        const int rl = wave * 16 + q4 * 4 + r;
                        if (cl > rl) s[nt][r] = -INFINITY;
                    }
                }
            }
            #pragma unroll
            for (int r = 0; r < 4; ++r) {
                float mt = fmaxf(fmaxf(s[0][r], s[1][r]), fmaxf(s[2][r], s[3][r]));
                mt = fmaxf(mt, __shfl_xor(mt, 1));
                mt = fmaxf(mt, __shfl_xor(mt, 2));
                mt = fmaxf(mt, __shfl_xor(mt, 4));
                mt = fmaxf(mt, __shfl_xor(mt, 8));
                const float mn = fmaxf(m_r[r], mt);
                const float al = __expf(m_r[r] - mn);
                m_r[r] = mn;
                const float p0 = __expf(s[0][r] - mn), p1 = __expf(s[1][r] - mn);
                const float p2 = __expf(s[2][r] - mn), p3 = __expf(s[3][r] - mn);
                Ps[wave][q4 * 4 + r][l15]      = f2bf_tr(p0);
                Ps[wave][q4 * 4 + r][16 + l15] = f2bf_tr(p1);
                Ps[wave][q4 * 4 + r][32 + l15] = f2bf_tr(p2);
                Ps[wave][q4 * 4 + r][48 + l15] = f2bf_tr(p3);
                float ps = p0 + p1 + p2 + p3;
                ps += __shfl_xor(ps, 1); ps += __shfl_xor(ps, 2);
                ps += __shfl_xor(ps, 4); ps += __shfl_xor(ps, 8);
                l_r[r] = l_r[r] * al + ps;
                #pragma unroll
                for (int d = 0; d < 8; ++d) oa[d][r] *= al;
            }
            const bf16x8 ap0 = *(const bf16x8*)&Ps[wave][l15][q4 * 8];
            const bf16x8 ap1 = *(const bf16x8*)&Ps[wave][l15][32 + q4 * 8];
            #pragma unroll
            for (int d = 0; d < 8; ++d) {
                const bf16x8 bv0 = *(const bf16x8*)&Vt[d * 16 + l15][(q4 ^ vkey7) * 8];
                const bf16x8 bv1 = *(const bf16x8*)&Vt[d * 16 + l15][((4 + q4) ^ vkey7) * 8];
                oa[d] = __builtin_amdgcn_mfma_f32_16x16x32_bf16(ap0, bv0, oa[d], 0, 0, 0);
                oa[d] = __builtin_amdgcn_mfma_f32_16x16x32_bf16(ap1, bv1, oa[d], 0, 0, 0);
            }
        }

        const int R0 = b * SEQ + tt * 64 + wave * 16 + q4 * 4;
        unsigned short* op = oPb + (size_t)h * NROWS * HD;
        #pragma unroll
        for (int d = 0; d < 8; ++d)
            #pragma unroll
            for (int r = 0; r < 4; ++r)
                op[(size_t)(R0 + r) * HD + d * 16 + l15] = f2bf_rne(oa[d][r]);
        if (l15 == 0) {
            #pragma unroll
            for (int r = 0; r < 4; ++r) {
                mP[h * NROWS + R0 + r] = m_r[r];
                lP[h * NROWS + R0 + r] = l_r[r];
            }
        }
    }
}

// ---------------------------------------------------------------------------
// merge the four kv-quarter partials; apply 1/l and OSCALE.
// ---------------------------------------------------------------------------
__global__ __launch_bounds__(256) void flash_merge(
    const unsigned short* __restrict__ oPb, const float* __restrict__ mP,
    const float* __restrict__ lP, float* __restrict__ out)
{
    const int idx = blockIdx.x * 256 + threadIdx.x;   // per float4
    const int r = idx >> 5, c = (idx & 31) * 4;
    float m[4], l[4];
    #pragma unroll
    for (int i = 0; i < 4; ++i) { m[i] = mP[i * NROWS + r]; l[i] = lP[i * NROWS + r]; }
    float M = fmaxf(fmaxf(m[0], m[1]), fmaxf(m[2], m[3]));
    float a[4], lsum = 0.f;
    #pragma unroll
    for (int i = 0; i < 4; ++i) { a[i] = __expf(m[i] - M); lsum += l[i] * a[i]; }
    const float inv = OSCALE / lsum;
    float ox = 0.f, oy = 0.f, oz = 0.f, ow = 0.f;
    #pragma unroll
    for (int i = 0; i < 4; ++i) {
        const ushort4 ov = *(const ushort4*)(oPb + (size_t)i * NROWS * HD + (size_t)r * HD + c);
        ox += a[i] * bf2f(ov.x); oy += a[i] * bf2f(ov.y);
        oz += a[i] * bf2f(ov.z); ow += a[i] * bf2f(ov.w);
    }
    float4 o; o.x = ox * inv; o.y = oy * inv; o.z = oz * inv; o.w = ow * inv;
    *(float4*)(out + (size_t)r * HD + c) = o;
}

// ---------------------------------------------------------------------------
extern "C" void kernel_launch(void* const* d_in, const int* in_sizes, int n_in,
                              void* d_out, int out_size, void* d_ws, size_t ws_size,
                              hipStream_t stream)
{
    (void)in_sizes; (void)n_in; (void)out_size; (void)ws_size;
    const float* x  = (const float*)d_in[0];
    const float* Wq = (const float*)d_in[1];
    const float* bq = (const float*)d_in[2];
    const float* Wk = (const float*)d_in[3];
    const float* bk = (const float*)d_in[4];
    const float* Wv = (const float*)d_in[5];
    const float* bv = (const float*)d_in[6];
    float* out = (float*)d_out;

    // workspace layout (bytes): ~41.4 MB total
    char* w = (char*)d_ws;
    unsigned short* qh  = (unsigned short*)(w);
    unsigned short* ql  = (unsigned short*)(w + 4194304);
    unsigned short* kh  = (unsigned short*)(w + 8388608);
    unsigned short* kl  = (unsigned short*)(w + 12582912);
    unsigned short* vth = (unsigned short*)(w + 16777216);
    unsigned short* wth = (unsigned short*)(w + 20971520);
    unsigned short* wtl = (unsigned short*)(w + 22544384);
    unsigned short* oPb = (unsigned short*)(w + 24117248);   // 4 x NROWS x HD bf16
    float* mP = (float*)(w + 40894464);                      // 4 x NROWS
    float* lP = (float*)(w + 41156608);                      // 4 x NROWS

    prep_w<<<dim3(32, 2, 3), 256, 0, stream>>>(Wq, Wk, Wv, wth, wtl);
    qkv_fused<<<512, 256, 0, stream>>>(x, bq, bk, bv, wth, wtl, qh, ql, kh, kl, vth);
    flash_mfma<<<512, 256, 0, stream>>>(qh, ql, kh, kl, vth, oPb, mP, lP);
    flash_merge<<<2048, 256, 0, stream>>>(oPb, mP, lP, out);
}